// Round 1
// baseline (363.450 us; speedup 1.0000x reference)
//
#include <hip/hip_runtime.h>
#include <stdint.h>

typedef __bf16 bf16x8 __attribute__((ext_vector_type(8)));
typedef float f32x4 __attribute__((ext_vector_type(4)));
typedef unsigned short ushort_t;

#define N_OUT 11008
#define K_DIM 4096
#define M_DIM 512
#define BM 256
#define BN 64
#define BK 64
#define KHALF 2048
#define NT 32 /* KHALF / BK */

__constant__ float c_nf4[16] = {
    -1.0f, -0.6961928009986877f, -0.5250730514526367f, -0.39491748809814453f,
    -0.28444138169288635f, -0.18477343022823334f, -0.09105003625154495f, 0.0f,
    0.07958029955625534f, 0.16093020141124725f, 0.24611230194568634f,
    0.33791524171829224f, 0.44070982933044434f, 0.5626170039176941f,
    0.7229568362236023f, 1.0f};

// round-half-up fp32 -> bf16, pack two into u32
__device__ __forceinline__ uint32_t pkbf(float lo, float hi) {
  uint32_t ul = __builtin_bit_cast(uint32_t, lo);
  uint32_t uh = __builtin_bit_cast(uint32_t, hi);
  return ((ul + 0x8000u) >> 16) | ((uh + 0x8000u) & 0xffff0000u);
}

__device__ __forceinline__ void async16(const void* g, void* l) {
  __builtin_amdgcn_global_load_lds(
      (const __attribute__((address_space(1))) void*)g,
      (__attribute__((address_space(3))) void*)l, 16, 0, 0);
}

__device__ __forceinline__ bf16x8 ldfrag(const ushort_t* p) {
  uint4 r = *reinterpret_cast<const uint4*>(p);
  return __builtin_bit_cast(bf16x8, r);
}

__device__ __forceinline__ uint32_t dq2(int a, int b, float s, const float2* lut) {
  float2 l = lut[a | (b << 4)];
  return pkbf(l.x * s, l.y * s);
}

// =============== fused prep: cvt+swizzle | x@A | B^T | bias-init =============
// grid: [0,1024) cvt, [1024,1536) xa, [1536,1579) bt, [1579,7083) bias-init
__global__ void k_prep(const float* __restrict__ x, const float* __restrict__ lA,
                       const float* __restrict__ lB, const float* __restrict__ bias,
                       ushort_t* __restrict__ xbf, ushort_t* __restrict__ xap,
                       ushort_t* __restrict__ btp, float* __restrict__ out) {
  const int b = blockIdx.x, t = threadIdx.x;
  if (b < 1024) {
    // x fp32 -> bf16 with XOR chunk swizzle inside each 64-elem k-window:
    // stored chunk position cp holds original chunk cp ^ (m&7)
    int oc = b * 256 + t;          // 16B output chunk id (8 bf16)
    int m = oc >> 9;               // 512 chunks per row
    int cr = oc & 511;
    int win = cr >> 3, cp = cr & 7;
    int c = cp ^ (m & 7);
    const float4* s4 = (const float4*)(x + (size_t)m * K_DIM + win * 64 + c * 8);
    float4 v0 = s4[0], v1 = s4[1];
    uint4 o;
    o.x = pkbf(v0.x, v0.y);
    o.y = pkbf(v0.z, v0.w);
    o.z = pkbf(v1.x, v1.y);
    o.w = pkbf(v1.z, v1.w);
    ((uint4*)xbf)[oc] = o;
  } else if (b < 1536) {
    // xa = 2*(x @ lora_A) for one row m, padded [512,32] bf16
    __shared__ float red[256 * 17];
    int m = b - 1024;
    int ks = t * 16;
    alignas(16) float xs[16];
    const f32x4* xv = (const f32x4*)(x + (size_t)m * K_DIM + ks);
    ((f32x4*)xs)[0] = xv[0];
    ((f32x4*)xs)[1] = xv[1];
    ((f32x4*)xs)[2] = xv[2];
    ((f32x4*)xs)[3] = xv[3];
    f32x4 ac0 = 0.f, ac1 = 0.f, ac2 = 0.f, ac3 = 0.f;
#pragma unroll
    for (int kk = 0; kk < 16; ++kk) {
      float xk = xs[kk];
      const f32x4* l4 = (const f32x4*)(lA + (size_t)(ks + kk) * 16);
      ac0 += xk * l4[0];
      ac1 += xk * l4[1];
      ac2 += xk * l4[2];
      ac3 += xk * l4[3];
    }
#pragma unroll
    for (int r = 0; r < 4; ++r) {
      red[t * 17 + r] = ac0[r];
      red[t * 17 + 4 + r] = ac1[r];
      red[t * 17 + 8 + r] = ac2[r];
      red[t * 17 + 12 + r] = ac3[r];
    }
    __syncthreads();
#pragma unroll
    for (int s = 128; s >= 16; s >>= 1) {
      if (t < s)
        for (int r = 0; r < 16; ++r) red[t * 17 + r] += red[(t + s) * 17 + r];
      __syncthreads();
    }
    if (t < 32) {
      float v = 0.f;
      if (t < 16) {
        for (int p = 0; p < 16; ++p) v += red[p * 17 + t];
        v *= 2.0f;  // SCALING
      }
      uint32_t u = __builtin_bit_cast(uint32_t, v);
      xap[(size_t)m * 32 + t] = (ushort_t)((u + 0x8000u) >> 16);
    }
  } else if (b < 1579) {
    // Bt = lora_B^T, padded [11008,32] bf16
    int o = (b - 1536) * 256 + t;
    uint32_t p[8];
#pragma unroll
    for (int j = 0; j < 8; ++j)
      p[j] = pkbf(lB[(size_t)(2 * j) * N_OUT + o], lB[(size_t)(2 * j + 1) * N_OUT + o]);
    uint4* dst = reinterpret_cast<uint4*>(btp + (size_t)o * 32);
    dst[0] = make_uint4(p[0], p[1], p[2], p[3]);
    dst[1] = make_uint4(p[4], p[5], p[6], p[7]);
    dst[2] = make_uint4(0u, 0u, 0u, 0u);
    dst[3] = make_uint4(0u, 0u, 0u, 0u);
  } else {
    // out = broadcast bias (split-K blocks atomically add on top)
    int i = (b - 1579) * 256 + t;  // float4 id, 1,409,024 total
    int col4 = i % 2752;           // 11008/4
    ((float4*)out)[i] = ((const float4*)bias)[col4];
  }
}

// =============== main fused GEMM (split-K=2, atomic epilogue) ===============
// BM=256 x BN=64, BK=64, 4 waves; wave w owns rows [w*64, w*64+64), acc 4x4.
// NEW single-barrier pipeline:
//   r1: dequant (compiler's vmcnt wait on prefetched indices FIFO-drains this
//       tile's A-DMA for free) -> ds_write into double-buffered lds_b
//   __syncthreads()  // vmcnt already 0 here -> barrier has no drain cost
//   r2: frag reads; lgkmcnt(0) (A-frag data landed -> single A buffer safe to
//       overwrite); issue next tile's A-DMA; sched_barrier pins DMA before the
//       index prefetch so the FIFO-drain invariant holds; 32 MFMA.
// DMA + index loads stay in flight across the whole MFMA phase + barrier.
__launch_bounds__(256, 3)
__global__ void k_main(const ushort_t* __restrict__ xbf, const int* __restrict__ wi,
                       const float* __restrict__ sc, const ushort_t* __restrict__ xap,
                       const ushort_t* __restrict__ btp, float* __restrict__ out) {
  __shared__ __align__(16) ushort_t lds_a[BM * BK];     // 32 KB, [row][c'], swizzled
  __shared__ __align__(16) ushort_t lds_b[2][BN * 72];  // 2 x 9 KB, +8 pad, dbuf
  __shared__ float2 lutp[256];                          // pair LUT, 2 KB

  const int t = threadIdx.x;
  const int lane = t & 63;
  const int w = t >> 6;

  // XCD-chunked bijective swizzle: 688 blocks = 8 XCDs x 86; work order is
  // x-major with the 4 (mblk,kh) siblings adjacent -> same XCD L2 serves the
  // shared B-index panel.
  const int n = blockIdx.x;
  const int wg = (n & 7) * 86 + (n >> 3);
  const int o0 = (wg >> 2) * BN;
  const int kh = (wg >> 1) & 1;
  const int m0 = (wg & 1) * BM;
  const int k0 = kh * KHALF;

  lutp[t] = make_float2(c_nf4[t & 15], c_nf4[t >> 4]);

  // B staging: thread -> (row=t>>2, 16 ints at (t&3)*16)
  const int brow = t >> 2, bq = t & 3;
  const int* gb = wi + (size_t)(o0 + brow) * K_DIM + k0 + bq * 16;
  const float* gs = sc + (size_t)(o0 + brow) * 64 + kh * 32;  // 1 scale/row/tile
  ushort_t* lb = &lds_b[0][brow * 72 + bq * 16];
  const int bstride = BN * 72;

  // A DMA: wave w stages its own rows [w*64, w*64+64); 8 instrs x 1KB
  const ushort_t* ga =
      xbf + (size_t)(m0 + w * 64 + (lane >> 3)) * K_DIM + k0 + (lane & 7) * 8;
  ushort_t* la_dst = lds_a + w * 4096 + lane * 8;

  f32x4 acc[4][4];
#pragma unroll
  for (int mi = 0; mi < 4; ++mi)
#pragma unroll
    for (int ni = 0; ni < 4; ++ni) acc[mi][ni] = (f32x4){0.f, 0.f, 0.f, 0.f};

  __syncthreads();  // lutp visible to all waves; nothing in flight yet

  // prologue: issue tile-0 A-DMA, THEN prefetch tile-0 indices+scale.
  // sched_barrier pins the order so any wait on the indices drains the DMA.
#pragma unroll
  for (int j = 0; j < 8; ++j) async16(ga + (size_t)j * 8 * K_DIM, la_dst + j * 512);
  __builtin_amdgcn_sched_barrier(0);
  int4 bi0 = ((const int4*)gb)[0], bi1 = ((const int4*)gb)[1];
  int4 bi2 = ((const int4*)gb)[2], bi3 = ((const int4*)gb)[3];
  float s = gs[0];
  gb += BK;
  uint4 braw;

  const ushort_t* afb = lds_a + (w * 64 + (lane & 15)) * BK;
  const int q = lane >> 4;
  const ushort_t* bfb = &lds_b[0][(lane & 15) * 72 + q * 8];

#pragma unroll 1
  for (int kt = 0; kt < NT; ++kt) {
    // ---- r1: dequant 16 idx -> 16 bf16 via pair LUT, 2x ds_write_b128 ----
    // (compiler inserts the vmcnt wait for bi here; FIFO order makes that
    //  wait also guarantee this tile's A-DMA has landed in lds_a)
    uint4 w0, w1;
    w0.x = dq2(bi0.x, bi0.y, s, lutp);
    w0.y = dq2(bi0.z, bi0.w, s, lutp);
    w0.z = dq2(bi1.x, bi1.y, s, lutp);
    w0.w = dq2(bi1.z, bi1.w, s, lutp);
    w1.x = dq2(bi2.x, bi2.y, s, lutp);
    w1.y = dq2(bi2.z, bi2.w, s, lutp);
    w1.z = dq2(bi3.x, bi3.y, s, lutp);
    w1.w = dq2(bi3.z, bi3.w, s, lutp);
    ushort_t* lbk = lb + (kt & 1) * bstride;
    *reinterpret_cast<uint4*>(lbk) = w0;
    *reinterpret_cast<uint4*>(lbk + 8) = w1;

    __syncthreads();  // b[kt&1] visible; vmcnt already 0 -> no drain cost

    // ---- r2: fragments + DMA/idx prefetch + 32 MFMA ----
    const ushort_t* bfbk = bfb + (kt & 1) * bstride;
#pragma unroll
    for (int kc = 0; kc < 2; ++kc) {
      const int cpr = ((kc * 4 + q) ^ (lane & 7)) * 8;  // un-swizzle
      bf16x8 av[4], bv[4];
#pragma unroll
      for (int mi = 0; mi < 4; ++mi) av[mi] = ldfrag(afb + mi * 16 * BK + cpr);
#pragma unroll
      for (int ni = 0; ni < 4; ++ni) bv[ni] = ldfrag(bfbk + ni * 16 * 72 + kc * 32);
      if (kc == 1) {
        // all A-frag reads (both kc) have returned -> safe to overwrite lds_a
        asm volatile("s_waitcnt lgkmcnt(0)" ::: "memory");
        if (kt + 1 < NT) {
#pragma unroll
          for (int j = 0; j < 8; ++j)
            async16(ga + (size_t)j * 8 * K_DIM + (kt + 1) * BK, la_dst + j * 512);
          __builtin_amdgcn_sched_barrier(0);  // pin: DMA before idx loads (FIFO)
          bi0 = ((const int4*)gb)[0];
          bi1 = ((const int4*)gb)[1];
          bi2 = ((const int4*)gb)[2];
          bi3 = ((const int4*)gb)[3];
          s = gs[kt + 1];
          gb += BK;
        } else if (kh == 1) {
          braw = *reinterpret_cast<const uint4*>(btp + (size_t)(o0 + brow) * 32 + bq * 8);
        }
      }
#pragma unroll
      for (int mi = 0; mi < 4; ++mi)
#pragma unroll
        for (int ni = 0; ni < 4; ++ni)
          acc[mi][ni] = __builtin_amdgcn_mfma_f32_16x16x32_bf16(av[mi], bv[ni],
                                                                acc[mi][ni], 0, 0, 0);
    }
  }

  // LoRA K-extension tail (kh==1 only): BK=32, A from xap, B from btp
  if (kh == 1) {
    __syncthreads();
    *reinterpret_cast<uint4*>(&lds_b[0][brow * 72 + bq * 8]) = braw;
#pragma unroll
    for (int j = 0; j < 4; ++j)
      async16(xap + (size_t)(m0 + w * 64 + j * 16 + (lane >> 2)) * 32 + (lane & 3) * 8,
              lds_a + w * 2048 + j * 512 + lane * 8);
    __syncthreads();
    bf16x8 av[4], bv[4];
#pragma unroll
    for (int mi = 0; mi < 4; ++mi)
      av[mi] = ldfrag(lds_a + w * 2048 + (mi * 16 + (lane & 15)) * 32 + q * 8);
#pragma unroll
    for (int ni = 0; ni < 4; ++ni)
      bv[ni] = ldfrag(&lds_b[0][(ni * 16 + (lane & 15)) * 72 + q * 8]);
#pragma unroll
    for (int mi = 0; mi < 4; ++mi)
#pragma unroll
      for (int ni = 0; ni < 4; ++ni)
        acc[mi][ni] = __builtin_amdgcn_mfma_f32_16x16x32_bf16(av[mi], bv[ni],
                                                              acc[mi][ni], 0, 0, 0);
  }

  // epilogue: atomic add onto bias-pre-initialized out
  const int cl = lane & 15, rg = q * 4;
#pragma unroll
  for (int ni = 0; ni < 4; ++ni) {
    int col = o0 + ni * 16 + cl;
#pragma unroll
    for (int mi = 0; mi < 4; ++mi) {
      int row0 = m0 + w * 64 + mi * 16 + rg;
      float* op = out + (size_t)row0 * N_OUT + col;
#pragma unroll
      for (int i = 0; i < 4; ++i) atomicAdd(op + (size_t)i * N_OUT, acc[mi][ni][i]);
    }
  }
}

extern "C" void kernel_launch(void* const* d_in, const int* in_sizes, int n_in,
                              void* d_out, int out_size, void* d_ws, size_t ws_size,
                              hipStream_t stream) {
  const float* x = (const float*)d_in[0];
  const int* wi = (const int*)d_in[1];
  const float* sc = (const float*)d_in[2];
  const float* lA = (const float*)d_in[3];
  const float* lB = (const float*)d_in[4];
  const float* bias = (const float*)d_in[5];
  float* out = (float*)d_out;

  char* wsb = (char*)d_ws;
  ushort_t* xbf = (ushort_t*)wsb;                               // 4 MB
  ushort_t* xap = (ushort_t*)(wsb + (4u << 20));                // 32 KB
  ushort_t* btp = (ushort_t*)(wsb + (4u << 20) + (32u << 10));  // 704 KB

  k_prep<<<7083, 256, 0, stream>>>(x, lA, lB, bias, xbf, xap, btp, out);
  k_main<<<688, 256, 0, stream>>>(xbf, wi, sc, xap, btp, out);
}